// Round 2
// baseline (27.471 us; speedup 1.0000x reference)
//
#include <hip/hip_runtime.h>
#include <hip/hip_bf16.h>

// Problem constants (fixed by setup_inputs)
#define BB 16
#define SS 1024
#define NW 8
#define QB 64   // q rows per block; 256 threads = 64 q x 4 heads

__global__ __launch_bounds__(256)
void mhaq_kernel(const float* __restrict__ x,      // (B,S,8) f32
                 const int*   __restrict__ mask,   // (B,S)
                 const float* __restrict__ theta,  // (8,)
                 const float* __restrict__ wout,   // (8,8)
                 float* __restrict__ out)          // (B,S,8) f32
{
    __shared__ float K[SS][NW];   // quantum-head features for this batch row (32 KB)
    __shared__ float MF[SS];      // mask factor 0/1 (4 KB)
    __shared__ float W[NW][NW];   // w_out (256 B)
    __shared__ float O[QB][NW];   // attention outputs before projection (2 KB)

    const int tid = threadIdx.x;
    const int b   = blockIdx.x >> 4;   // 16 q-chunks per batch row
    const int qc  = blockIdx.x & 15;

    float th[NW];
#pragma unroll
    for (int e = 0; e < NW; ++e) th[e] = theta[e];

    // --- quantum head, closed form. g_i = cos(x_i + theta_i)
    // h_0 = g1*g2*...*g7 ; h_w = g0*...*gw (w>=1)
    const float* xb = x + (size_t)b * SS * NW;
#pragma unroll
    for (int i = 0; i < 4; ++i) {
        const int k = tid + 256 * i;
        const float4 r0 = *reinterpret_cast<const float4*>(xb + (size_t)k * NW);
        const float4 r1 = *reinterpret_cast<const float4*>(xb + (size_t)k * NW + 4);
        float g[NW];
        g[0] = __cosf(r0.x + th[0]);
        g[1] = __cosf(r0.y + th[1]);
        g[2] = __cosf(r0.z + th[2]);
        g[3] = __cosf(r0.w + th[3]);
        g[4] = __cosf(r1.x + th[4]);
        g[5] = __cosf(r1.y + th[5]);
        g[6] = __cosf(r1.z + th[6]);
        g[7] = __cosf(r1.w + th[7]);
        const float h1 = g[0] * g[1];
        const float h2 = h1 * g[2];
        const float h3 = h2 * g[3];
        const float h4 = h3 * g[4];
        const float h5 = h4 * g[5];
        const float h6 = h5 * g[6];
        const float h7 = h6 * g[7];
        const float t12 = g[1] * g[2], t34 = g[3] * g[4], t56 = g[5] * g[6];
        const float h0 = (t12 * t34) * (t56 * g[7]);
        *reinterpret_cast<float4*>(&K[k][0]) = make_float4(h0, h1, h2, h3);
        *reinterpret_cast<float4*>(&K[k][4]) = make_float4(h4, h5, h6, h7);
        MF[k] = (mask[b * SS + k] != 0) ? 1.0f : 0.0f;
    }
    if (tid < NW * NW) W[tid >> 3][tid & 7] = wout[tid];
    __syncthreads();

    // --- attention: thread = (q row, head). head_dim=2, scores in [-sqrt2, sqrt2]
    // -> softmax needs no max subtraction.
    const float is2 = 0.70710678118654752f;  // 1/sqrt(head_dim)
    const int ql = tid >> 2;
    const int hd = tid & 3;
    const int qg = qc * QB + ql;
    const float qu = K[qg][2 * hd]     * is2;
    const float qv = K[qg][2 * hd + 1] * is2;

    float d = 0.f, a0 = 0.f, a1 = 0.f;
#pragma unroll 8
    for (int k = 0; k < SS; ++k) {
        const float u = K[k][2 * hd];
        const float v = K[k][2 * hd + 1];
        const float s = __builtin_fmaf(qu, u, qv * v);
        const float w = __expf(s) * MF[k];
        d += w;
        a0 = __builtin_fmaf(w, u, a0);
        a1 = __builtin_fmaf(w, v, a1);
    }
    const float invd = 1.0f / d;
    O[ql][2 * hd]     = a0 * invd;
    O[ql][2 * hd + 1] = a1 * invd;
    __syncthreads();

    // --- output projection: out = O @ W^T, write f32
#pragma unroll
    for (int idx = tid; idx < QB * NW; idx += 256) {
        const int q = idx >> 3, e = idx & 7;
        float s = 0.f;
#pragma unroll
        for (int f = 0; f < NW; ++f) s = __builtin_fmaf(O[q][f], W[e][f], s);
        out[((size_t)(b * SS + qc * QB + q)) * NW + e] = s;
    }
}

extern "C" void kernel_launch(void* const* d_in, const int* in_sizes, int n_in,
                              void* d_out, int out_size, void* d_ws, size_t ws_size,
                              hipStream_t stream) {
    const float* x     = (const float*)d_in[0];
    const int*   mask  = (const int*)d_in[1];
    const float* theta = (const float*)d_in[2];
    const float* wout  = (const float*)d_in[3];
    float* out = (float*)d_out;

    dim3 grid(BB * (SS / QB));  // 256 blocks
    dim3 block(256);
    mhaq_kernel<<<grid, block, 0, stream>>>(x, mask, theta, wout, out);
}

// Round 3
// 19.595 us; speedup vs baseline: 1.4019x; 1.4019x over previous
//
#include <hip/hip_runtime.h>

// Problem constants (fixed by setup_inputs)
#define BB 16
#define SS 1024
#define NW 8
#define QB 64            // q rows per block
#define HS (2 * SS + 8)  // padded per-head LDS plane stride (words); +8 spreads banks

__global__ __launch_bounds__(1024)
void mhaq_kernel(const float* __restrict__ x,      // (B,S,8) f32
                 const int*   __restrict__ mask,   // (B,S)
                 const float* __restrict__ theta,  // (8,)
                 const float* __restrict__ wout,   // (8,8)
                 float* __restrict__ out)          // (B,S,8) f32
{
    __shared__ float Kt[4 * HS];   // per-head (u,v) pairs, mask-folded (~32.9 KB)
    __shared__ float O[QB][NW];    // attention outputs pre-projection
    __shared__ float W[NW * NW];   // w_out

    const int tid = threadIdx.x;
    const int b   = blockIdx.x >> 4;   // 16 q-chunks per batch row
    const int qc  = blockIdx.x & 15;

    float th[NW];
#pragma unroll
    for (int e = 0; e < NW; ++e) th[e] = theta[e];

    // ---- stage quantum head for row k = tid, closed form, mask folded in.
    // g_i = cos(x_i + theta_i); h_0 = g1..g7, h_w = g0..gw (w>=1)
    float mf;
    {
        const float* xr = x + ((size_t)b * SS + tid) * NW;
        const float4 r0 = *reinterpret_cast<const float4*>(xr);
        const float4 r1 = *reinterpret_cast<const float4*>(xr + 4);
        float g[NW];
        g[0] = __cosf(r0.x + th[0]); g[1] = __cosf(r0.y + th[1]);
        g[2] = __cosf(r0.z + th[2]); g[3] = __cosf(r0.w + th[3]);
        g[4] = __cosf(r1.x + th[4]); g[5] = __cosf(r1.y + th[5]);
        g[6] = __cosf(r1.z + th[6]); g[7] = __cosf(r1.w + th[7]);
        float h[NW];
        h[1] = g[0] * g[1]; h[2] = h[1] * g[2]; h[3] = h[2] * g[3];
        h[4] = h[3] * g[4]; h[5] = h[4] * g[5]; h[6] = h[5] * g[6];
        h[7] = h[6] * g[7];
        h[0] = (g[1] * g[2]) * (g[3] * g[4]) * ((g[5] * g[6]) * g[7]);
        mf = (mask[b * SS + tid] != 0) ? 1.0f : 0.0f;
#pragma unroll
        for (int p = 0; p < 4; ++p)
            *reinterpret_cast<float2*>(&Kt[p * HS + 2 * tid]) =
                make_float2(h[2 * p] * mf, h[2 * p + 1] * mf);
    }
    if (tid < NW * NW) W[tid] = wout[tid];
    // masked-key count (each masked key contributes exp2(0)=1 to d); also the barrier
    const int cm = __syncthreads_count(mf == 0.0f);

    // ---- per-thread role: (q row, head, k-slice)
    const int ql = tid >> 4;         // 0..63
    const int hd = (tid >> 2) & 3;   // 0..3
    const int ks = tid & 3;          // 0..3  (k-slice, reduced via shfl)
    const int qg = qc * QB + ql;

    // q fragment: UNMASKED features, recomputed from x; fold (1/sqrt(2))*log2(e)
    float qu, qv;
    {
        const float* xq = x + ((size_t)b * SS + qg) * NW;
        const float4 r0 = *reinterpret_cast<const float4*>(xq);
        const float4 r1 = *reinterpret_cast<const float4*>(xq + 4);
        float g[NW];
        g[0] = __cosf(r0.x + th[0]); g[1] = __cosf(r0.y + th[1]);
        g[2] = __cosf(r0.z + th[2]); g[3] = __cosf(r0.w + th[3]);
        g[4] = __cosf(r1.x + th[4]); g[5] = __cosf(r1.y + th[5]);
        g[6] = __cosf(r1.z + th[6]); g[7] = __cosf(r1.w + th[7]);
        float h[NW];
        h[1] = g[0] * g[1]; h[2] = h[1] * g[2]; h[3] = h[2] * g[3];
        h[4] = h[3] * g[4]; h[5] = h[4] * g[5]; h[6] = h[5] * g[6];
        h[7] = h[6] * g[7];
        h[0] = (g[1] * g[2]) * (g[3] * g[4]) * ((g[5] * g[6]) * g[7]);
        const float CF = 0.70710678118654752f * 1.44269504088896340f;
        qu = h[2 * hd] * CF;
        qv = h[2 * hd + 1] * CF;
    }

    // ---- no-max softmax over this thread's 256 k's (scores in [-sqrt2,sqrt2]).
    // k pair per iter: (8j+2ks, 8j+2ks+1) -> ds_read_b128, ~2-way banks (free)
    const float* kp = &Kt[hd * HS];
    float d0 = 0.f, d1 = 0.f, a0 = 0.f, a1 = 0.f;
#pragma unroll 8
    for (int j = 0; j < SS / 8; ++j) {
        const float4 uv = *reinterpret_cast<const float4*>(&kp[16 * j + 4 * ks]);
        const float s0 = __builtin_fmaf(qu, uv.x, qv * uv.y);
        const float s1 = __builtin_fmaf(qu, uv.z, qv * uv.w);
        const float w0 = __builtin_amdgcn_exp2f(s0);
        const float w1 = __builtin_amdgcn_exp2f(s1);
        d0 += w0;
        d1 += w1;
        a0 = __builtin_fmaf(w0, uv.x, a0);
        a1 = __builtin_fmaf(w0, uv.y, a1);
        a0 = __builtin_fmaf(w1, uv.z, a0);
        a1 = __builtin_fmaf(w1, uv.w, a1);
    }
    float d = d0 + d1;
    d  += __shfl_xor(d, 1);  d  += __shfl_xor(d, 2);
    a0 += __shfl_xor(a0, 1); a0 += __shfl_xor(a0, 2);
    a1 += __shfl_xor(a1, 1); a1 += __shfl_xor(a1, 2);
    if (ks == 0) {
        const float inv = 1.0f / (d - (float)cm);  // remove masked keys' exp(0)=1
        O[ql][2 * hd]     = a0 * inv;
        O[ql][2 * hd + 1] = a1 * inv;
    }
    __syncthreads();

    // ---- output projection: out = O @ W^T (f32)
    if (tid < QB * NW) {
        const int q = tid >> 3, e = tid & 7;
        float s = 0.f;
#pragma unroll
        for (int f = 0; f < NW; ++f) s = __builtin_fmaf(O[q][f], W[e * NW + f], s);
        out[((size_t)(b * SS + qc * QB + q)) * NW + e] = s;
    }
}

extern "C" void kernel_launch(void* const* d_in, const int* in_sizes, int n_in,
                              void* d_out, int out_size, void* d_ws, size_t ws_size,
                              hipStream_t stream) {
    const float* x     = (const float*)d_in[0];
    const int*   mask  = (const int*)d_in[1];
    const float* theta = (const float*)d_in[2];
    const float* wout  = (const float*)d_in[3];
    float* out = (float*)d_out;

    dim3 grid(BB * (SS / QB));  // 256 blocks, 1 per CU
    dim3 block(1024);           // 64q x 4head x 4 k-slices = 16 waves/CU
    mhaq_kernel<<<grid, block, 0, stream>>>(x, mask, theta, wout, out);
}

// Round 4
// 17.765 us; speedup vs baseline: 1.5464x; 1.1030x over previous
//
#include <hip/hip_runtime.h>

// Problem constants (fixed by setup_inputs)
#define BB 16
#define SS 1024
#define NW 8
#define QB 64
#define PS 1032   // LDS plane stride in words; 1032 % 32 == 8 spreads heads across banks

typedef float v2f __attribute__((ext_vector_type(2)));

__global__ __launch_bounds__(1024)
void mhaq_kernel(const float* __restrict__ x,      // (B,S,8) f32
                 const int*   __restrict__ mask,   // (B,S)
                 const float* __restrict__ theta,  // (8,)
                 const float* __restrict__ wout,   // (8,8)
                 float* __restrict__ out)          // (B,S,8) f32
{
    __shared__ float P[8 * PS];    // U planes [hd][PS] (mask-folded), then V planes
    __shared__ float Qf[QB][NW];   // unmasked q features, pre-scaled by log2e/sqrt(2)
    __shared__ float O[QB][NW];    // attention outputs pre-projection
    __shared__ float W[NW * NW];   // w_out

    const int tid = threadIdx.x;
    const int b   = blockIdx.x >> 4;
    const int qc  = blockIdx.x & 15;

    float th[NW];
#pragma unroll
    for (int e = 0; e < NW; ++e) th[e] = theta[e];

    // ---- stage quantum head for row k = tid (closed form), mask folded into K planes.
    // g_i = cos(x_i + theta_i); h_0 = g1..g7, h_w = g0..gw (w>=1)
    {
        const float* xr = x + ((size_t)b * SS + tid) * NW;
        const float4 r0 = *reinterpret_cast<const float4*>(xr);
        const float4 r1 = *reinterpret_cast<const float4*>(xr + 4);
        float g[NW];
        g[0] = __cosf(r0.x + th[0]); g[1] = __cosf(r0.y + th[1]);
        g[2] = __cosf(r0.z + th[2]); g[3] = __cosf(r0.w + th[3]);
        g[4] = __cosf(r1.x + th[4]); g[5] = __cosf(r1.y + th[5]);
        g[6] = __cosf(r1.z + th[6]); g[7] = __cosf(r1.w + th[7]);
        float h[NW];
        h[1] = g[0] * g[1]; h[2] = h[1] * g[2]; h[3] = h[2] * g[3];
        h[4] = h[3] * g[4]; h[5] = h[4] * g[5]; h[6] = h[5] * g[6];
        h[7] = h[6] * g[7];
        h[0] = (g[1] * g[2]) * (g[3] * g[4]) * ((g[5] * g[6]) * g[7]);
        const float mf = (mask[b * SS + tid] != 0) ? 1.0f : 0.0f;
#pragma unroll
        for (int p = 0; p < 4; ++p) {
            P[p * PS + tid]       = h[2 * p]     * mf;  // U plane
            P[(4 + p) * PS + tid] = h[2 * p + 1] * mf;  // V plane
        }
        const int r = tid - qc * QB;
        if ((unsigned)r < (unsigned)QB) {  // this row is one of the block's q-rows
            const float CF = 0.70710678118654752f * 1.44269504088896340f;
#pragma unroll
            for (int w = 0; w < NW; ++w) Qf[r][w] = h[w] * CF;
        }
        if (tid < NW * NW) W[tid] = wout[tid];
        // masked-key count (each masked key contributes exp2(0)=1 to d); also the barrier
        const int cm = __syncthreads_count(mf == 0.0f);

        // ---- per-thread role: 4 q-rows, one head, 1-of-16 k-slices (interleaved chunks of 4)
        const int qg = tid >> 6;         // 0..15 == wave id; q-rows qg*4..qg*4+3
        const int hd = (tid >> 4) & 3;   // 0..3
        const int ks = tid & 15;         // 0..15

        float qu[4], qv[4];
#pragma unroll
        for (int i = 0; i < 4; ++i) {
            qu[i] = Qf[qg * 4 + i][2 * hd];
            qv[i] = Qf[qg * 4 + i][2 * hd + 1];
        }

        v2f vd[4], va0[4], va1[4];
#pragma unroll
        for (int i = 0; i < 4; ++i) { vd[i] = (v2f){0.f, 0.f}; va0[i] = (v2f){0.f, 0.f}; va1[i] = (v2f){0.f, 0.f}; }

        const int base0 = hd * PS + 4 * ks;
#pragma unroll
        for (int t = 0; t < 16; ++t) {
            const int a = base0 + 64 * t;
            const float4 Ur = *reinterpret_cast<const float4*>(&P[a]);
            const float4 Vr = *reinterpret_cast<const float4*>(&P[4 * PS + a]);
            const v2f ulo = (v2f){Ur.x, Ur.y}, uhi = (v2f){Ur.z, Ur.w};
            const v2f vlo = (v2f){Vr.x, Vr.y}, vhi = (v2f){Vr.z, Vr.w};
#pragma unroll
            for (int i = 0; i < 4; ++i) {
                const v2f qup = (v2f){qu[i], qu[i]};
                const v2f qvp = (v2f){qv[i], qv[i]};
                const v2f slo = __builtin_elementwise_fma(qup, ulo, qvp * vlo);
                const v2f shi = __builtin_elementwise_fma(qup, uhi, qvp * vhi);
                const v2f wlo = (v2f){__builtin_amdgcn_exp2f(slo.x), __builtin_amdgcn_exp2f(slo.y)};
                const v2f whi = (v2f){__builtin_amdgcn_exp2f(shi.x), __builtin_amdgcn_exp2f(shi.y)};
                vd[i]  += wlo + whi;
                va0[i] = __builtin_elementwise_fma(wlo, ulo, va0[i]);
                va0[i] = __builtin_elementwise_fma(whi, uhi, va0[i]);
                va1[i] = __builtin_elementwise_fma(wlo, vlo, va1[i]);
                va1[i] = __builtin_elementwise_fma(whi, vhi, va1[i]);
            }
        }

        // ---- collapse packed lanes, reduce across the 16 k-slices (low 4 lane bits)
        float dd[4], a0[4], a1[4];
#pragma unroll
        for (int i = 0; i < 4; ++i) {
            dd[i] = vd[i].x + vd[i].y;
            a0[i] = va0[i].x + va0[i].y;
            a1[i] = va1[i].x + va1[i].y;
        }
#pragma unroll
        for (int m = 1; m <= 8; m <<= 1) {
#pragma unroll
            for (int i = 0; i < 4; ++i) {
                dd[i] += __shfl_xor(dd[i], m);
                a0[i] += __shfl_xor(a0[i], m);
                a1[i] += __shfl_xor(a1[i], m);
            }
        }
        if (ks == 0) {
#pragma unroll
            for (int i = 0; i < 4; ++i) {
                const float inv = 1.0f / (dd[i] - (float)cm);
                O[qg * 4 + i][2 * hd]     = a0[i] * inv;
                O[qg * 4 + i][2 * hd + 1] = a1[i] * inv;
            }
        }
    }
    __syncthreads();

    // ---- output projection: out = O @ W^T (f32)
    if (tid < QB * NW) {
        const int q = tid >> 3, e = tid & 7;
        float s = 0.f;
#pragma unroll
        for (int f = 0; f < NW; ++f) s = __builtin_fmaf(O[q][f], W[e * NW + f], s);
        out[((size_t)(b * SS + qc * QB + q)) * NW + e] = s;
    }
}

extern "C" void kernel_launch(void* const* d_in, const int* in_sizes, int n_in,
                              void* d_out, int out_size, void* d_ws, size_t ws_size,
                              hipStream_t stream) {
    const float* x     = (const float*)d_in[0];
    const int*   mask  = (const int*)d_in[1];
    const float* theta = (const float*)d_in[2];
    const float* wout  = (const float*)d_in[3];
    float* out = (float*)d_out;

    dim3 grid(BB * (SS / QB));  // 256 blocks, 1 per CU
    dim3 block(1024);           // 16 waves/CU
    mhaq_kernel<<<grid, block, 0, stream>>>(x, mask, theta, wout, out);
}